// Round 6
// baseline (184.309 us; speedup 1.0000x reference)
//
#include <hip/hip_runtime.h>

#define N_NODES 50000
#define N_PAD 50176    // 392 * 128 (gemm grid coverage) == 1568 * 32
#define N_EDGES 800000
#define C 128
#define CAP 48         // per-node CSR slot; deg ~ Poisson(16), P(>48) ~ 3e-11
#define SC_B 782       // scatter blocks: 200192 threads x 4 edges
#define TOBF_B 6250    // tobf16 blocks (1.6M float4 / 256)
#define ZPAD_B 11      // zero xh pad rows 50000..50175 (2816 uint4)
#define PACK_B 16      // W-pack blocks (4096 threads at 256/block)
#define PLANE_U ((size_t)N_PAD * 32)   // ushorts per 32-col plane (3.2 MB)
#define GS_B 6272      // gather_slice blocks: 4 slices x 1568 chunks, XCD-pinned

typedef unsigned short ushort_t;
typedef unsigned int uint_t;
typedef __attribute__((ext_vector_type(8))) short bf16x8;
typedef __attribute__((ext_vector_type(4))) float f32x4;

// ---------------- fp32 -> bf16 (RNE) ----------------
__device__ __forceinline__ uint_t f2bf(float f) {
    uint_t u = __float_as_uint(f);
    u += 0x7fffu + ((u >> 16) & 1u);
    return u >> 16;
}
__device__ __forceinline__ float bflo(uint_t u) { return __uint_as_float(u << 16); }
__device__ __forceinline__ float bfhi(uint_t u) { return __uint_as_float(u & 0xffff0000u); }

// ---- prep: direct CSR scatter (1 global atomic + 1 ushort write per edge;
// independent, pipelined — no LDS passes, no sort kernel needed) | tobf16
// into 4-plane column-sliced layout | pad-zero | W-pack. One grid. ----
__global__ __launch_bounds__(256) void prep_kernel(
    const int* __restrict__ src, const int* __restrict__ dst,
    int* __restrict__ cursor, ushort_t* __restrict__ epad,
    const float* __restrict__ x, ushort_t* __restrict__ xh,
    const float* __restrict__ W1l, const float* __restrict__ W1r,
    ushort_t* __restrict__ Bp) {
    int b = blockIdx.x;
    int t = threadIdx.x;
    if (b < SC_B) {
        int tid = b * 256 + t;                 // 0..200191; 200000 active
        if (tid < N_EDGES / 4) {
            int4 s4 = ((const int4*)src)[tid];
            int4 d4 = ((const int4*)dst)[tid];
            int ss[4] = {s4.x, s4.y, s4.z, s4.w};
            int dd[4] = {d4.x, d4.y, d4.z, d4.w};
            #pragma unroll
            for (int i = 0; i < 4; i++) {
                int pos = atomicAdd(&cursor[dd[i]], 1);
                if (pos < CAP) epad[dd[i] * CAP + pos] = (ushort_t)ss[i];
            }
        }
    } else if (b < SC_B + TOBF_B) {
        int i = (b - SC_B) * 256 + t;   // one float4 per thread; 1.6M exact
        float4 v = ((const float4*)x)[i];
        uint_t lo = f2bf(v.x) | (f2bf(v.y) << 16);
        uint_t hi = f2bf(v.z) | (f2bf(v.w) << 16);
        int node = i >> 5, c = i & 31;          // 32 float4 per node row
        int plane = c >> 3, part = c & 7;       // 8 float4 per plane strip
        ((uint2*)(xh + (size_t)plane * PLANE_U + node * 32 + part * 4))[0] =
            make_uint2(lo, hi);
    } else if (b < SC_B + TOBF_B + ZPAD_B) {
        int i = (b - SC_B - TOBF_B) * 256 + t;   // 0..2815 active (4*704)
        if (i < 2816) {
            int plane = i / 704, rem = i % 704;  // 704 uint4 per plane pad
            int node = N_NODES + (rem >> 2), part = rem & 3;
            ((uint4*)(xh + (size_t)plane * PLANE_U + node * 32 + part * 8))[0] =
                make_uint4(0, 0, 0, 0);
        }
    } else {
        // Bp[((nt*8+kk)*64 + lane)*8 + j] = Wcat[kk*32 + (lane>>4)*8 + j][nt*16 + (lane&15)]
        int p = (b - SC_B - TOBF_B - ZPAD_B) * 256 + t;   // 0..4095
        int lane = p & 63;
        int pair = p >> 6;          // (nt*8 + kk)
        int kk = pair & 7;
        int nt = pair >> 3;
        int n = lane & 15, quad = lane >> 4;
        int col = nt * 16 + n;
        int k0 = kk * 32 + quad * 8;
        uint_t w[4];
        #pragma unroll
        for (int jj = 0; jj < 4; jj++) {
            int ka = k0 + 2 * jj, kb = k0 + 2 * jj + 1;
            float fa = (ka < C) ? W1l[ka * C + col] : W1r[(ka - C) * C + col];
            float fb = (kb < C) ? W1l[kb * C + col] : W1r[(kb - C) * C + col];
            w[jj] = f2bf(fa) | (f2bf(fb) << 16);
        }
        ((uint4*)(Bp + (size_t)p * 8))[0] = make_uint4(w[0], w[1], w[2], w[3]);
    }
}

// accumulate 8 bf16 (packed in uint4) into a[0..7] (fp32)
__device__ __forceinline__ void bf8_acc(float* a, const uint4 v) {
    a[0] += bflo(v.x); a[1] += bfhi(v.x);
    a[2] += bflo(v.y); a[3] += bfhi(v.y);
    a[4] += bflo(v.z); a[5] += bfhi(v.z);
    a[6] += bflo(v.w); a[7] += bfhi(v.w);
}

// ---- gather_slice: XCD-pinned column-sliced mean aggregation.
// block b -> slice s=(b&7)>>1 (blockIdx%8 ~ XCD round-robin), chunk of 32 nodes.
// Each XCD only touches ONE 3.2MB plane -> L2-resident after compulsory fills.
// 4 lanes x 16B per edge row-slice; 8 edges in flight per lane (MLP). ----
__global__ __launch_bounds__(128) void gather_slice(
    const ushort_t* __restrict__ xh, const ushort_t* __restrict__ epad,
    const int* __restrict__ cursor, ushort_t* __restrict__ msb) {
    int b = blockIdx.x, t = threadIdx.x;
    int slice = (b & 7) >> 1;
    int chunk = (b >> 3) * 2 + (b & 1);       // 0..1567
    int g = t >> 2, lane = t & 3;
    int node = chunk * 32 + g;
    int d = cursor[node];
    int dd = d < CAP ? d : CAP;
    const ushort_t* lst = epad + node * CAP;
    const ushort_t* plane = xh + (size_t)slice * PLANE_U + lane * 8;

    float a[8] = {0,0,0,0,0,0,0,0};
    float c8[8] = {0,0,0,0,0,0,0,0};
    int e = 0;
    for (; e + 8 <= dd; e += 8) {
        int s0 = lst[e + 0], s1 = lst[e + 1], s2 = lst[e + 2], s3 = lst[e + 3];
        int s4 = lst[e + 4], s5 = lst[e + 5], s6 = lst[e + 6], s7 = lst[e + 7];
        uint4 v0 = *(const uint4*)(plane + (size_t)s0 * 32);
        uint4 v1 = *(const uint4*)(plane + (size_t)s1 * 32);
        uint4 v2 = *(const uint4*)(plane + (size_t)s2 * 32);
        uint4 v3 = *(const uint4*)(plane + (size_t)s3 * 32);
        uint4 v4 = *(const uint4*)(plane + (size_t)s4 * 32);
        uint4 v5 = *(const uint4*)(plane + (size_t)s5 * 32);
        uint4 v6 = *(const uint4*)(plane + (size_t)s6 * 32);
        uint4 v7 = *(const uint4*)(plane + (size_t)s7 * 32);
        bf8_acc(a, v0); bf8_acc(c8, v1); bf8_acc(a, v2); bf8_acc(c8, v3);
        bf8_acc(a, v4); bf8_acc(c8, v5); bf8_acc(a, v6); bf8_acc(c8, v7);
    }
    for (; e + 4 <= dd; e += 4) {
        int s0 = lst[e + 0], s1 = lst[e + 1], s2 = lst[e + 2], s3 = lst[e + 3];
        uint4 v0 = *(const uint4*)(plane + (size_t)s0 * 32);
        uint4 v1 = *(const uint4*)(plane + (size_t)s1 * 32);
        uint4 v2 = *(const uint4*)(plane + (size_t)s2 * 32);
        uint4 v3 = *(const uint4*)(plane + (size_t)s3 * 32);
        bf8_acc(a, v0); bf8_acc(c8, v1); bf8_acc(a, v2); bf8_acc(c8, v3);
    }
    for (; e < dd; e++) {
        uint4 v = *(const uint4*)(plane + (size_t)lst[e] * 32);
        bf8_acc(a, v);
    }
    float inv = 1.0f / fmaxf((float)d, 1.0f);
    uint4 o;
    o.x = f2bf((a[0] + c8[0]) * inv) | (f2bf((a[1] + c8[1]) * inv) << 16);
    o.y = f2bf((a[2] + c8[2]) * inv) | (f2bf((a[3] + c8[3]) * inv) << 16);
    o.z = f2bf((a[4] + c8[4]) * inv) | (f2bf((a[5] + c8[5]) * inv) << 16);
    o.w = f2bf((a[6] + c8[6]) * inv) | (f2bf((a[7] + c8[7]) * inv) << 16);
    ((uint4*)(msb + (size_t)node * C + slice * 32 + lane * 8))[0] = o;
}

// ---------------- gemm (MFMA, LDS-staged B): h = relu([ms|xs]@[W1l;W1r]+b1l) ----------------
__global__ __launch_bounds__(512) void gemm_mfma(
    const ushort_t* __restrict__ msb, const ushort_t* __restrict__ xh,
    const ushort_t* __restrict__ Bp, const float* __restrict__ b1l,
    const float* __restrict__ W2l, const float* __restrict__ W2r,
    const float* __restrict__ b2l, float* __restrict__ z, float* __restrict__ out) {
    __shared__ ushort_t sB[2 * C * C];   // 64 KB
    int t = threadIdx.x;
    #pragma unroll
    for (int i = 0; i < 8; i++)
        ((uint4*)sB)[i * 512 + t] = ((const uint4*)Bp)[i * 512 + t];
    __syncthreads();

    int wid = t >> 6, lane = t & 63;
    int m = lane & 15, quad = lane >> 4;
    int base = blockIdx.x * 128 + wid * 16;   // node base for this wave
    int node = base + m;

    const ushort_t* a_ms = msb + (size_t)node * C + quad * 8;
    bf16x8 aw[8];
    #pragma unroll
    for (int kk = 0; kk < 4; kk++) aw[kk] = *(const bf16x8*)(a_ms + kk * 32);
    #pragma unroll
    for (int kk = 0; kk < 4; kk++)
        aw[4 + kk] = *(const bf16x8*)(xh + (size_t)kk * PLANE_U + node * 32 + quad * 8);

    f32x4 acc[8];
    #pragma unroll
    for (int nt = 0; nt < 8; nt++) acc[nt] = (f32x4){0.f, 0.f, 0.f, 0.f};

    const bf16x8* bp = (const bf16x8*)sB;
    #pragma unroll
    for (int kk = 0; kk < 8; kk++) {
        bf16x8 a = aw[kk];
        #pragma unroll
        for (int nt = 0; nt < 8; nt++) {
            bf16x8 bfr = bp[(nt * 8 + kk) * 64 + lane];   // ds_read_b128
            acc[nt] = __builtin_amdgcn_mfma_f32_16x16x32_bf16(a, bfr, acc[nt], 0, 0, 0);
        }
    }

    float zz0[4] = {0,0,0,0}, zz1[4] = {0,0,0,0};
    float rr0[4] = {0,0,0,0}, rr1[4] = {0,0,0,0};
    #pragma unroll
    for (int nt = 0; nt < 8; nt++) {
        int col = nt * 16 + m;
        float bias = b1l[col];
        float2 wl = ((const float2*)W2l)[col];
        float2 wr = ((const float2*)W2r)[col];
        #pragma unroll
        for (int reg = 0; reg < 4; reg++) {
            float h = fmaxf(acc[nt][reg] + bias, 0.0f);
            zz0[reg] = fmaf(h, wl.x, zz0[reg]);
            zz1[reg] = fmaf(h, wl.y, zz1[reg]);
            rr0[reg] = fmaf(h, wr.x, rr0[reg]);
            rr1[reg] = fmaf(h, wr.y, rr1[reg]);
        }
    }
    float bl0 = b2l[0], bl1 = b2l[1];
    #pragma unroll
    for (int reg = 0; reg < 4; reg++) {
        float a0 = zz0[reg], a1 = zz1[reg], c0 = rr0[reg], c1 = rr1[reg];
        #pragma unroll
        for (int off = 8; off > 0; off >>= 1) {
            a0 += __shfl_down(a0, off, 16);
            a1 += __shfl_down(a1, off, 16);
            c0 += __shfl_down(c0, off, 16);
            c1 += __shfl_down(c1, off, 16);
        }
        if (m == 0) {
            int onode = base + quad * 4 + reg;
            if (onode < N_NODES) {
                z[onode * 2 + 0]   = a0;
                z[onode * 2 + 1]   = a1;
                out[onode * 2 + 0] = c0 + bl0;
                out[onode * 2 + 1] = c1 + bl1;
            }
        }
    }
}

// ---------------- final: out[n] += mean_{j in N(n)} z[j], 16 lanes/node ----------------
__global__ __launch_bounds__(256) void final_kernel(
    const float* __restrict__ z, const ushort_t* __restrict__ epad,
    const int* __restrict__ cursor, float* __restrict__ out) {
    int t = threadIdx.x;
    int sub = t & 15;
    int node = blockIdx.x * 16 + (t >> 4);   // 3125 blocks -> exactly 50000
    int d = cursor[node];
    int dd = d < CAP ? d : CAP;
    const ushort_t* lst = epad + node * CAP;
    float a0 = 0.0f, a1 = 0.0f;
    for (int e = sub; e < dd; e += 16) {
        float2 v = ((const float2*)z)[lst[e]];
        a0 += v.x; a1 += v.y;
    }
    #pragma unroll
    for (int off = 8; off > 0; off >>= 1) {
        a0 += __shfl_down(a0, off);
        a1 += __shfl_down(a1, off);
    }
    if (sub == 0) {
        float inv = 1.0f / fmaxf((float)d, 1.0f);
        out[node * 2 + 0] += a0 * inv;
        out[node * 2 + 1] += a1 * inv;
    }
}

extern "C" void kernel_launch(void* const* d_in, const int* in_sizes, int n_in,
                              void* d_out, int out_size, void* d_ws, size_t ws_size,
                              hipStream_t stream) {
    const float* x   = (const float*)d_in[0];
    const int*   ei  = (const int*)d_in[1];   // (2, 800000) row-major
    const float* W1l = (const float*)d_in[2];
    const float* b1l = (const float*)d_in[3];
    const float* W1r = (const float*)d_in[4];
    const float* W2l = (const float*)d_in[5];
    const float* b2l = (const float*)d_in[6];
    const float* W2r = (const float*)d_in[7];
    float* out = (float*)d_out;

    const int* src = ei;
    const int* dst = ei + N_EDGES;

    // workspace (4-byte units):
    // cursor[N_PAD] | epad ushort[N_PAD*CAP = 4.8MB] | xh 4-plane[12.8MB] |
    // msb[12.8MB] | Bp[64KB] | z[400KB]
    int* cursor    = (int*)d_ws;
    ushort_t* epad = (ushort_t*)(cursor + N_PAD);
    ushort_t* xh   = epad + (size_t)N_PAD * CAP;
    ushort_t* msb  = xh + 4 * PLANE_U;
    ushort_t* Bp   = msb + (size_t)N_PAD * C;
    float* z       = (float*)(Bp + 2 * C * C);

    hipMemsetAsync(cursor, 0, N_PAD * sizeof(int), stream);

    prep_kernel<<<SC_B + TOBF_B + ZPAD_B + PACK_B, 256, 0, stream>>>(
        src, dst, cursor, epad, x, xh, W1l, W1r, Bp);
    gather_slice<<<GS_B, 128, 0, stream>>>(xh, epad, cursor, msb);
    gemm_mfma<<<392, 512, 0, stream>>>(msb, xh, Bp, b1l, W2l, W2r, b2l, z, out);
    final_kernel<<<N_NODES / 16, 256, 0, stream>>>(z, epad, cursor, out);
}

// Round 8
// 143.764 us; speedup vs baseline: 1.2820x; 1.2820x over previous
//
#include <hip/hip_runtime.h>

#define N_NODES 50000
#define N_PAD 50176    // 392 * 128 (gemm grid coverage) == 1568 * 32
#define N_EDGES 800000
#define C 128
#define NB 784         // buckets of 64 dst nodes (dst>>6)
#define NPB 64         // nodes per bucket
#define CBCAP 1408     // bucket capacity: Poisson(1020) + 12 sigma
#define B1_BUCK 98     // phase1 bucket blocks: 8192 edges each (2-pass)
#define TOBF_B 6250    // tobf16 blocks (1.6M float4 / 256)
#define ZPAD_B 11      // zero xh pad rows 50000..50175 (2816 uint4)
#define PACK_B 16      // W-pack blocks (4096 threads at 256/block)
#define PLANE_U ((size_t)N_PAD * 32)   // ushorts per 32-col plane (3.2 MB)
#define GS_B 6272      // gather_slice blocks: 4 slices x 1568 chunks, XCD-pinned

typedef unsigned short ushort_t;
typedef unsigned int uint_t;
typedef __attribute__((ext_vector_type(8))) short bf16x8;
typedef __attribute__((ext_vector_type(4))) float f32x4;

// ---------------- fp32 -> bf16 (RNE) ----------------
__device__ __forceinline__ uint_t f2bf(float f) {
    uint_t u = __float_as_uint(f);
    u += 0x7fffu + ((u >> 16) & 1u);
    return u >> 16;
}
__device__ __forceinline__ float bflo(uint_t u) { return __uint_as_float(u << 16); }
__device__ __forceinline__ float bfhi(uint_t u) { return __uint_as_float(u & 0xffff0000u); }

// ---- phase 1: bucket edges by dst>>6 into packed 4B records (src<<16|dst).
// 98 blocks x 8192 edges, two-pass (count, reserve once, scatter): 77k global
// atomics (4x fewer than 1-pass/391-block) and ~10-edge consecutive runs per
// (block,bucket) -> ~4x less cb write amplification (round-6 lesson inverted).
// tobf16 / pad-zero / W-pack fused in the same grid. ----
__global__ __launch_bounds__(256) void bucket1_kernel(
    const int* __restrict__ src, const int* __restrict__ dst,
    int* __restrict__ gcur, uint_t* __restrict__ cb,
    const float* __restrict__ x, ushort_t* __restrict__ xh,
    const float* __restrict__ W1l, const float* __restrict__ W1r,
    ushort_t* __restrict__ Bp) {
    int b = blockIdx.x;
    int t = threadIdx.x;
    if (b < B1_BUCK) {
        __shared__ int hist[NB];
        __shared__ int offs[NB];
        for (int i = t; i < NB; i += 256) hist[i] = 0;
        __syncthreads();
        // pass 1: count (dst only)
        #pragma unroll
        for (int it = 0; it < 4; it++) {
            int tid = b * 1024 + it * 256 + t;   // 8-edge units; 100000 active
            if (tid < N_EDGES / 8) {
                int4 d0 = ((const int4*)dst)[2 * tid];
                int4 d1 = ((const int4*)dst)[2 * tid + 1];
                atomicAdd(&hist[d0.x >> 6], 1);
                atomicAdd(&hist[d0.y >> 6], 1);
                atomicAdd(&hist[d0.z >> 6], 1);
                atomicAdd(&hist[d0.w >> 6], 1);
                atomicAdd(&hist[d1.x >> 6], 1);
                atomicAdd(&hist[d1.y >> 6], 1);
                atomicAdd(&hist[d1.z >> 6], 1);
                atomicAdd(&hist[d1.w >> 6], 1);
            }
        }
        __syncthreads();
        for (int i = t; i < NB; i += 256) {
            offs[i] = atomicAdd(&gcur[i], hist[i]);   // reserve run space (once)
            hist[i] = 0;
        }
        __syncthreads();
        // pass 2: scatter (edges re-read; L2-warm, 64KB/block)
        #pragma unroll 1
        for (int it = 0; it < 4; it++) {
            int tid = b * 1024 + it * 256 + t;
            if (tid < N_EDGES / 8) {
                int4 s0 = ((const int4*)src)[2 * tid];
                int4 s1 = ((const int4*)src)[2 * tid + 1];
                int4 d0 = ((const int4*)dst)[2 * tid];
                int4 d1 = ((const int4*)dst)[2 * tid + 1];
                int ss[8] = {s0.x, s0.y, s0.z, s0.w, s1.x, s1.y, s1.z, s1.w};
                int dd[8] = {d0.x, d0.y, d0.z, d0.w, d1.x, d1.y, d1.z, d1.w};
                #pragma unroll
                for (int i = 0; i < 8; i++) {
                    int bkt = dd[i] >> 6;
                    int pos = offs[bkt] + atomicAdd(&hist[bkt], 1);
                    if (pos < CBCAP)
                        cb[(size_t)bkt * CBCAP + pos] =
                            ((uint_t)ss[i] << 16) | (uint_t)dd[i];
                }
            }
        }
    } else if (b < B1_BUCK + TOBF_B) {
        int i = (b - B1_BUCK) * 256 + t;   // one float4 per thread; 1.6M exact
        float4 v = ((const float4*)x)[i];
        uint_t lo = f2bf(v.x) | (f2bf(v.y) << 16);
        uint_t hi = f2bf(v.z) | (f2bf(v.w) << 16);
        int node = i >> 5, c = i & 31;          // 32 float4 per node row
        int plane = c >> 3, part = c & 7;       // 8 float4 per plane strip
        ((uint2*)(xh + (size_t)plane * PLANE_U + node * 32 + part * 4))[0] =
            make_uint2(lo, hi);
    } else if (b < B1_BUCK + TOBF_B + ZPAD_B) {
        int i = (b - B1_BUCK - TOBF_B) * 256 + t;   // 0..2815 active (4*704)
        if (i < 2816) {
            int plane = i / 704, rem = i % 704;  // 704 uint4 per plane pad
            int node = N_NODES + (rem >> 2), part = rem & 3;
            ((uint4*)(xh + (size_t)plane * PLANE_U + node * 32 + part * 8))[0] =
                make_uint4(0, 0, 0, 0);
        }
    } else {
        // Bp[((nt*8+kk)*64 + lane)*8 + j] = Wcat[kk*32 + (lane>>4)*8 + j][nt*16 + (lane&15)]
        int p = (b - B1_BUCK - TOBF_B - ZPAD_B) * 256 + t;   // 0..4095
        int lane = p & 63;
        int pair = p >> 6;          // (nt*8 + kk)
        int kk = pair & 7;
        int nt = pair >> 3;
        int n = lane & 15, quad = lane >> 4;
        int col = nt * 16 + n;
        int k0 = kk * 32 + quad * 8;
        uint_t w[4];
        #pragma unroll
        for (int jj = 0; jj < 4; jj++) {
            int ka = k0 + 2 * jj, kb = k0 + 2 * jj + 1;
            float fa = (ka < C) ? W1l[ka * C + col] : W1r[(ka - C) * C + col];
            float fb = (kb < C) ? W1l[kb * C + col] : W1r[(kb - C) * C + col];
            w[jj] = f2bf(fa) | (f2bf(fb) << 16);
        }
        ((uint4*)(Bp + (size_t)p * 8))[0] = make_uint4(w[0], w[1], w[2], w[3]);
    }
}

// ---- sort: one block per 64-dst-node bucket. Counting sort by local node
// (hardware ds int atomics) into LDS, persist CSR (ushort src ids). ----
__global__ __launch_bounds__(256) void sort_kernel(
    const int* __restrict__ gcur, const uint_t* __restrict__ cb,
    ushort_t* __restrict__ esorted, int* __restrict__ nodeoff,
    int* __restrict__ cursor) {
    __shared__ uint_t srun[CBCAP];         // 5.6 KB
    __shared__ ushort_t sidx[CBCAP];       // 2.8 KB
    __shared__ int cnt[NPB], offs[NPB], cur[NPB];
    int b = blockIdx.x, t = threadIdx.x;
    if (t < NPB) { cnt[t] = 0; cur[t] = 0; }
    __syncthreads();

    int len = gcur[b];
    if (len > CBCAP) len = CBCAP;
    const uint_t* run = cb + (size_t)b * CBCAP;
    for (int e = t; e < len; e += 256) {
        uint_t rec = run[e];
        srun[e] = rec;
        atomicAdd(&cnt[rec & (NPB - 1)], 1);
    }
    __syncthreads();

    // exclusive prefix sum of 64 counts on wave 0
    if (t < 64) {
        int v = cnt[t];
        int s = v;
        #pragma unroll
        for (int o = 1; o < 64; o <<= 1) {
            int u = __shfl_up(s, o, 64);
            if (t >= o) s += u;
        }
        offs[t] = s - v;
    }
    __syncthreads();

    for (int e = t; e < len; e += 256) {
        uint_t rec = srun[e];
        int local = rec & (NPB - 1);
        int pos = offs[local] + atomicAdd(&cur[local], 1);
        sidx[pos] = (ushort_t)(rec >> 16);
    }
    __syncthreads();

    // persist CSR (ushort, paired into uint writes)
    for (int e = t; 2 * e < len; e += 256) {
        uint_t v = (uint_t)sidx[2 * e];
        if (2 * e + 1 < len) v |= (uint_t)sidx[2 * e + 1] << 16;
        ((uint_t*)esorted)[(size_t)b * (CBCAP / 2) + e] = v;
    }
    if (t < NPB) {
        int g = b * NPB + t;
        nodeoff[g] = b * CBCAP + offs[t];
        cursor[g] = cnt[t];
    }
}

// accumulate 8 bf16 (packed in uint4) into a[0..7] (fp32)
__device__ __forceinline__ void bf8_acc(float* a, const uint4 v) {
    a[0] += bflo(v.x); a[1] += bfhi(v.x);
    a[2] += bflo(v.y); a[3] += bfhi(v.y);
    a[4] += bflo(v.z); a[5] += bfhi(v.z);
    a[6] += bflo(v.w); a[7] += bfhi(v.w);
}

// ---- gather_slice: XCD-pinned column-sliced mean aggregation.
// block b -> slice s=(b&7)>>1 (blockIdx%8 ~ XCD round-robin), chunk of 32 nodes.
// Each XCD only touches ONE 3.2MB plane -> L2-resident after compulsory fills.
// 4 lanes x 16B per edge row-slice; 8 edges in flight per lane (MLP). ----
__global__ __launch_bounds__(128) void gather_slice(
    const ushort_t* __restrict__ xh, const ushort_t* __restrict__ esorted,
    const int* __restrict__ nodeoff, const int* __restrict__ cursor,
    ushort_t* __restrict__ msb) {
    int b = blockIdx.x, t = threadIdx.x;
    int slice = (b & 7) >> 1;
    int chunk = (b >> 3) * 2 + (b & 1);       // 0..1567
    int g = t >> 2, lane = t & 3;
    int node = chunk * 32 + g;
    int d = cursor[node];
    const ushort_t* lst = esorted + nodeoff[node];
    const ushort_t* plane = xh + (size_t)slice * PLANE_U + lane * 8;

    float a[8] = {0,0,0,0,0,0,0,0};
    float c8[8] = {0,0,0,0,0,0,0,0};
    int e = 0;
    for (; e + 8 <= d; e += 8) {
        int s0 = lst[e + 0], s1 = lst[e + 1], s2 = lst[e + 2], s3 = lst[e + 3];
        int s4 = lst[e + 4], s5 = lst[e + 5], s6 = lst[e + 6], s7 = lst[e + 7];
        uint4 v0 = *(const uint4*)(plane + (size_t)s0 * 32);
        uint4 v1 = *(const uint4*)(plane + (size_t)s1 * 32);
        uint4 v2 = *(const uint4*)(plane + (size_t)s2 * 32);
        uint4 v3 = *(const uint4*)(plane + (size_t)s3 * 32);
        uint4 v4 = *(const uint4*)(plane + (size_t)s4 * 32);
        uint4 v5 = *(const uint4*)(plane + (size_t)s5 * 32);
        uint4 v6 = *(const uint4*)(plane + (size_t)s6 * 32);
        uint4 v7 = *(const uint4*)(plane + (size_t)s7 * 32);
        bf8_acc(a, v0); bf8_acc(c8, v1); bf8_acc(a, v2); bf8_acc(c8, v3);
        bf8_acc(a, v4); bf8_acc(c8, v5); bf8_acc(a, v6); bf8_acc(c8, v7);
    }
    for (; e + 4 <= d; e += 4) {
        int s0 = lst[e + 0], s1 = lst[e + 1], s2 = lst[e + 2], s3 = lst[e + 3];
        uint4 v0 = *(const uint4*)(plane + (size_t)s0 * 32);
        uint4 v1 = *(const uint4*)(plane + (size_t)s1 * 32);
        uint4 v2 = *(const uint4*)(plane + (size_t)s2 * 32);
        uint4 v3 = *(const uint4*)(plane + (size_t)s3 * 32);
        bf8_acc(a, v0); bf8_acc(c8, v1); bf8_acc(a, v2); bf8_acc(c8, v3);
    }
    for (; e < d; e++) {
        uint4 v = *(const uint4*)(plane + (size_t)lst[e] * 32);
        bf8_acc(a, v);
    }
    float inv = 1.0f / fmaxf((float)d, 1.0f);
    uint4 o;
    o.x = f2bf((a[0] + c8[0]) * inv) | (f2bf((a[1] + c8[1]) * inv) << 16);
    o.y = f2bf((a[2] + c8[2]) * inv) | (f2bf((a[3] + c8[3]) * inv) << 16);
    o.z = f2bf((a[4] + c8[4]) * inv) | (f2bf((a[5] + c8[5]) * inv) << 16);
    o.w = f2bf((a[6] + c8[6]) * inv) | (f2bf((a[7] + c8[7]) * inv) << 16);
    ((uint4*)(msb + (size_t)node * C + slice * 32 + lane * 8))[0] = o;
}

// ---------------- gemm (MFMA, LDS-staged B): h = relu([ms|xs]@[W1l;W1r]+b1l) ----------------
__global__ __launch_bounds__(512) void gemm_mfma(
    const ushort_t* __restrict__ msb, const ushort_t* __restrict__ xh,
    const ushort_t* __restrict__ Bp, const float* __restrict__ b1l,
    const float* __restrict__ W2l, const float* __restrict__ W2r,
    const float* __restrict__ b2l, float* __restrict__ z, float* __restrict__ out) {
    __shared__ ushort_t sB[2 * C * C];   // 64 KB
    int t = threadIdx.x;
    #pragma unroll
    for (int i = 0; i < 8; i++)
        ((uint4*)sB)[i * 512 + t] = ((const uint4*)Bp)[i * 512 + t];
    __syncthreads();

    int wid = t >> 6, lane = t & 63;
    int m = lane & 15, quad = lane >> 4;
    int base = blockIdx.x * 128 + wid * 16;   // node base for this wave
    int node = base + m;

    const ushort_t* a_ms = msb + (size_t)node * C + quad * 8;
    bf16x8 aw[8];
    #pragma unroll
    for (int kk = 0; kk < 4; kk++) aw[kk] = *(const bf16x8*)(a_ms + kk * 32);
    #pragma unroll
    for (int kk = 0; kk < 4; kk++)
        aw[4 + kk] = *(const bf16x8*)(xh + (size_t)kk * PLANE_U + node * 32 + quad * 8);

    f32x4 acc[8];
    #pragma unroll
    for (int nt = 0; nt < 8; nt++) acc[nt] = (f32x4){0.f, 0.f, 0.f, 0.f};

    const bf16x8* bp = (const bf16x8*)sB;
    #pragma unroll
    for (int kk = 0; kk < 8; kk++) {
        bf16x8 a = aw[kk];
        #pragma unroll
        for (int nt = 0; nt < 8; nt++) {
            bf16x8 bfr = bp[(nt * 8 + kk) * 64 + lane];   // ds_read_b128
            acc[nt] = __builtin_amdgcn_mfma_f32_16x16x32_bf16(a, bfr, acc[nt], 0, 0, 0);
        }
    }

    float zz0[4] = {0,0,0,0}, zz1[4] = {0,0,0,0};
    float rr0[4] = {0,0,0,0}, rr1[4] = {0,0,0,0};
    #pragma unroll
    for (int nt = 0; nt < 8; nt++) {
        int col = nt * 16 + m;
        float bias = b1l[col];
        float2 wl = ((const float2*)W2l)[col];
        float2 wr = ((const float2*)W2r)[col];
        #pragma unroll
        for (int reg = 0; reg < 4; reg++) {
            float h = fmaxf(acc[nt][reg] + bias, 0.0f);
            zz0[reg] = fmaf(h, wl.x, zz0[reg]);
            zz1[reg] = fmaf(h, wl.y, zz1[reg]);
            rr0[reg] = fmaf(h, wr.x, rr0[reg]);
            rr1[reg] = fmaf(h, wr.y, rr1[reg]);
        }
    }
    float bl0 = b2l[0], bl1 = b2l[1];
    #pragma unroll
    for (int reg = 0; reg < 4; reg++) {
        float a0 = zz0[reg], a1 = zz1[reg], c0 = rr0[reg], c1 = rr1[reg];
        #pragma unroll
        for (int off = 8; off > 0; off >>= 1) {
            a0 += __shfl_down(a0, off, 16);
            a1 += __shfl_down(a1, off, 16);
            c0 += __shfl_down(c0, off, 16);
            c1 += __shfl_down(c1, off, 16);
        }
        if (m == 0) {
            int onode = base + quad * 4 + reg;
            if (onode < N_NODES) {
                z[onode * 2 + 0]   = a0;
                z[onode * 2 + 1]   = a1;
                out[onode * 2 + 0] = c0 + bl0;
                out[onode * 2 + 1] = c1 + bl1;
            }
        }
    }
}

// ---------------- final: out[n] += mean_{j in N(n)} z[j] via CSR, 16 lanes/node ----------------
__global__ __launch_bounds__(256) void final_kernel(
    const float* __restrict__ z, const int* __restrict__ nodeoff,
    const int* __restrict__ cursor, const ushort_t* __restrict__ esorted,
    float* __restrict__ out) {
    int t = threadIdx.x;
    int sub = t & 15;
    int node = blockIdx.x * 16 + (t >> 4);   // 3125 blocks -> exactly 50000
    int d = cursor[node];
    const ushort_t* lst = esorted + nodeoff[node];
    float a0 = 0.0f, a1 = 0.0f;
    for (int e = sub; e < d; e += 16) {
        float2 v = ((const float2*)z)[lst[e]];
        a0 += v.x; a1 += v.y;
    }
    #pragma unroll
    for (int off = 8; off > 0; off >>= 1) {
        a0 += __shfl_down(a0, off);
        a1 += __shfl_down(a1, off);
    }
    if (sub == 0) {
        float inv = 1.0f / fmaxf((float)d, 1.0f);
        out[node * 2 + 0] += a0 * inv;
        out[node * 2 + 1] += a1 * inv;
    }
}

extern "C" void kernel_launch(void* const* d_in, const int* in_sizes, int n_in,
                              void* d_out, int out_size, void* d_ws, size_t ws_size,
                              hipStream_t stream) {
    const float* x   = (const float*)d_in[0];
    const int*   ei  = (const int*)d_in[1];   // (2, 800000) row-major
    const float* W1l = (const float*)d_in[2];
    const float* b1l = (const float*)d_in[3];
    const float* W1r = (const float*)d_in[4];
    const float* W2l = (const float*)d_in[5];
    const float* b2l = (const float*)d_in[6];
    const float* W2r = (const float*)d_in[7];
    float* out = (float*)d_out;

    const int* src = ei;
    const int* dst = ei + N_EDGES;

    // workspace (4-byte units):
    // gcur[1024] | cb uint[NB*CBCAP = 4.4MB] | esorted ushort[NB*CBCAP = 2.2MB] |
    // nodeoff[N_PAD] | cursor[N_PAD] | xh 4-plane[12.8MB] | msb[12.8MB] | Bp | z
    int* gcur         = (int*)d_ws;
    uint_t* cb        = (uint_t*)(gcur + 1024);
    ushort_t* esorted = (ushort_t*)(cb + (size_t)NB * CBCAP);
    int* nodeoff      = (int*)(esorted + (size_t)NB * CBCAP);
    int* cursor       = nodeoff + N_PAD;
    ushort_t* xh      = (ushort_t*)(cursor + N_PAD);
    ushort_t* msb     = xh + 4 * PLANE_U;
    ushort_t* Bp      = msb + (size_t)N_PAD * C;
    float* z          = (float*)(Bp + 2 * C * C);

    hipMemsetAsync(gcur, 0, NB * sizeof(int), stream);

    bucket1_kernel<<<B1_BUCK + TOBF_B + ZPAD_B + PACK_B, 256, 0, stream>>>(
        src, dst, gcur, cb, x, xh, W1l, W1r, Bp);
    sort_kernel<<<NB, 256, 0, stream>>>(gcur, cb, esorted, nodeoff, cursor);
    gather_slice<<<GS_B, 128, 0, stream>>>(xh, esorted, nodeoff, cursor, msb);
    gemm_mfma<<<392, 512, 0, stream>>>(msb, xh, Bp, b1l, W2l, W2r, b2l, z, out);
    final_kernel<<<N_NODES / 16, 256, 0, stream>>>(z, nodeoff, cursor, esorted, out);
}